// Round 1
// baseline (477.656 us; speedup 1.0000x reference)
//
#include <hip/hip_runtime.h>

// SSIM loss, fused single-pass implementation.
// imgs: (32, 3, 512, 512) fp32. Output: scalar 1 - mean(ssim_map).
//
// Gaussian 11x11 (sigma=1.5) is separable: w2d = outer(g,g).
// Zero-padded SAME conv == separable conv with zero-fill halo in LDS.
// Per block: 32x32 output tile, 42x42 input tile (halo=5).
//   phase 1: load img1/img2 tiles to LDS (0 outside image = conv zero pad)
//   phase 2: horizontal blur of {x1, x2, x1^2, x2^2, x1*x2} -> 5 LDS arrays [42][32]
//   phase 3: vertical blur + SSIM formula + block-reduce -> atomicAdd to d_ws[0]
// finalize kernel: out[0] = 1 - sum/NPIX.

#define HH 512
#define WW 512
#define TILE 32
#define RAD 5
#define IN_TILE 42          // TILE + 2*RAD
#define S_STRIDE 44         // padded row stride for input tiles
#define NPLANES 96          // 32*3
#define NPIX 25165824.0f    // 32*3*512*512

// Gaussian weights, sigma=1.5, normalized (computed offline in double).
__constant__ float c_g[11] = {
    1.0283800e-03f, 7.5987600e-03f, 3.6000770e-02f, 1.0936072e-01f,
    2.1300560e-01f, 2.6601170e-01f, 2.1300560e-01f, 1.0936072e-01f,
    3.6000770e-02f, 7.5987600e-03f, 1.0283800e-03f};

__global__ __launch_bounds__(256) void ssim_fused_kernel(
    const float* __restrict__ img1, const float* __restrict__ img2,
    float* __restrict__ sum_out) {
  __shared__ float s1[IN_TILE][S_STRIDE];
  __shared__ float s2[IN_TILE][S_STRIDE];
  __shared__ float h0[IN_TILE][TILE];  // blur_h(x1)
  __shared__ float h1[IN_TILE][TILE];  // blur_h(x2)
  __shared__ float h2[IN_TILE][TILE];  // blur_h(x1*x1)
  __shared__ float h3[IN_TILE][TILE];  // blur_h(x2*x2)
  __shared__ float h4[IN_TILE][TILE];  // blur_h(x1*x2)
  __shared__ float wsum[4];

  const int tid = threadIdx.x;
  const int tx = blockIdx.x * TILE;  // output tile origin x
  const int ty = blockIdx.y * TILE;  // output tile origin y
  const size_t base = (size_t)blockIdx.z * (HH * WW);

  // ---- phase 1: global -> LDS, zero-fill halo outside image ----
  for (int idx = tid; idx < IN_TILE * IN_TILE; idx += 256) {
    int r = idx / IN_TILE;
    int c = idx - r * IN_TILE;
    int gy = ty - RAD + r;
    int gx = tx - RAD + c;
    float v1 = 0.f, v2 = 0.f;
    if ((unsigned)gy < (unsigned)HH && (unsigned)gx < (unsigned)WW) {
      size_t off = base + (size_t)gy * WW + gx;
      v1 = img1[off];
      v2 = img2[off];
    }
    s1[r][c] = v1;
    s2[r][c] = v2;
  }
  __syncthreads();

  // ---- phase 2: horizontal blur of the 5 quantities ----
  for (int idx = tid; idx < IN_TILE * TILE; idx += 256) {
    int r = idx >> 5;   // / TILE
    int c = idx & 31;   // % TILE
    float a0 = 0.f, a1 = 0.f, a2 = 0.f, a3 = 0.f, a4 = 0.f;
#pragma unroll
    for (int dx = 0; dx < 11; ++dx) {
      float w = c_g[dx];
      float v1 = s1[r][c + dx];
      float v2 = s2[r][c + dx];
      a0 += w * v1;
      a1 += w * v2;
      a2 += w * (v1 * v1);
      a3 += w * (v2 * v2);
      a4 += w * (v1 * v2);
    }
    h0[r][c] = a0;
    h1[r][c] = a1;
    h2[r][c] = a2;
    h3[r][c] = a3;
    h4[r][c] = a4;
  }
  __syncthreads();

  // ---- phase 3: vertical blur + SSIM + reduce ----
  const float C1 = 1e-4f;   // 0.01^2
  const float C2 = 9e-4f;   // 0.03^2
  float lsum = 0.f;
  for (int idx = tid; idx < TILE * TILE; idx += 256) {
    int r = idx >> 5;
    int c = idx & 31;
    float mu1 = 0.f, mu2 = 0.f, b11 = 0.f, b22 = 0.f, b12 = 0.f;
#pragma unroll
    for (int dy = 0; dy < 11; ++dy) {
      float w = c_g[dy];
      mu1 += w * h0[r + dy][c];
      mu2 += w * h1[r + dy][c];
      b11 += w * h2[r + dy][c];
      b22 += w * h3[r + dy][c];
      b12 += w * h4[r + dy][c];
    }
    float mu1sq = mu1 * mu1;
    float mu2sq = mu2 * mu2;
    float mu12 = mu1 * mu2;
    float sig11 = b11 - mu1sq;
    float sig22 = b22 - mu2sq;
    float sig12 = b12 - mu12;
    float num = (2.f * mu12 + C1) * (2.f * sig12 + C2);
    float den = (mu1sq + mu2sq + C1) * (sig11 + sig22 + C2);
    lsum += num / den;
  }

  // wave (64-lane) reduction
#pragma unroll
  for (int off = 32; off > 0; off >>= 1)
    lsum += __shfl_down(lsum, off, 64);
  int lane = tid & 63;
  int wid = tid >> 6;
  if (lane == 0) wsum[wid] = lsum;
  __syncthreads();
  if (tid == 0) {
    float b = wsum[0] + wsum[1] + wsum[2] + wsum[3];
    atomicAdd(sum_out, b);
  }
}

__global__ void ssim_finalize_kernel(const float* __restrict__ sum_in,
                                     float* __restrict__ out) {
  out[0] = 1.0f - sum_in[0] * (1.0f / NPIX);
}

extern "C" void kernel_launch(void* const* d_in, const int* in_sizes, int n_in,
                              void* d_out, int out_size, void* d_ws, size_t ws_size,
                              hipStream_t stream) {
  const float* img1 = (const float*)d_in[0];
  const float* img2 = (const float*)d_in[1];
  float* out = (float*)d_out;
  float* acc = (float*)d_ws;

  // d_ws is poisoned 0xAA before every launch -> zero the accumulator.
  hipMemsetAsync(acc, 0, sizeof(float), stream);

  dim3 grid(WW / TILE, HH / TILE, NPLANES);
  ssim_fused_kernel<<<grid, 256, 0, stream>>>(img1, img2, acc);
  ssim_finalize_kernel<<<1, 1, 0, stream>>>(acc, out);
}

// Round 2
// 335.542 us; speedup vs baseline: 1.4235x; 1.4235x over previous
//
#include <hip/hip_runtime.h>

// SSIM loss, fused single-pass, round 2.
// imgs: (32, 3, 512, 512) fp32. Output: scalar 1 - mean(ssim_map).
//
// Changes vs round 1:
//  - img1/img2 interleaved as float2 in LDS (1 ds_read_b64 per tap in phase 2)
//  - (mu1,mu2) and (b11,b22) carried as 2-wide ext-vectors (pk-fma friendly)
//  - phase 3: 4 consecutive rows per thread, sliding 14-tap window
//    (42 LDS reads per 4 outputs instead of 220); h stride 33 for bank spread
//  - fp32 divide -> v_rcp_f32
//  - staging: float2 global loads + ds_write_b128
//  - 256 accumulator slots to spread atomic contention

#define HH 512
#define WW 512
#define TILE 32
#define RADY 5
#define RADX 6              // left halo 6 (even alignment for float2 loads)
#define IN_ROWS 42          // TILE + 2*RADY
#define IN_COLS 44          // TILE + 12 (cols tx-6 .. tx+37; taps use +1..+42)
#define S_STRIDE 44         // float2 stride of s12
#define H_STRIDE 33         // padded stride of h arrays
#define NPLANES 96
#define NPIX 25165824.0f
#define NACC 256

typedef float v2f __attribute__((ext_vector_type(2)));
typedef float v4f __attribute__((ext_vector_type(4)));

__constant__ float c_g[11] = {
    1.0283800e-03f, 7.5987600e-03f, 3.6000770e-02f, 1.0936072e-01f,
    2.1300560e-01f, 2.6601170e-01f, 2.1300560e-01f, 1.0936072e-01f,
    3.6000770e-02f, 7.5987600e-03f, 1.0283800e-03f};

__global__ __launch_bounds__(256) void ssim_fused_kernel(
    const float* __restrict__ img1, const float* __restrict__ img2,
    float* __restrict__ acc) {
  __shared__ v2f s12[IN_ROWS][S_STRIDE];    // (x1, x2) interleaved
  __shared__ v2f h01[IN_ROWS][H_STRIDE];    // (blur_h x1, blur_h x2)
  __shared__ v2f h23[IN_ROWS][H_STRIDE];    // (blur_h x1^2, blur_h x2^2)
  __shared__ float h4[IN_ROWS][H_STRIDE];   // blur_h (x1*x2)
  __shared__ float wsum[4];

  const int tid = threadIdx.x;
  const int tx = blockIdx.x * TILE;
  const int ty = blockIdx.y * TILE;
  const size_t base = (size_t)blockIdx.z * (HH * WW);

  // ---- phase 1: global -> LDS, float2-pair loads, b128 interleaved store ----
  // 42 rows x 22 float2-pairs = 924 pair-elements
  for (int idx = tid; idx < IN_ROWS * (IN_COLS / 2); idx += 256) {
    int r = idx / (IN_COLS / 2);
    int p = idx - r * (IN_COLS / 2);
    int gy = ty - RADY + r;
    int gx = tx - RADX + 2 * p;           // even
    v4f val = {0.f, 0.f, 0.f, 0.f};
    if ((unsigned)gy < (unsigned)HH && (unsigned)gx < (unsigned)WW) {
      size_t off = base + (size_t)gy * WW + gx;
      const v2f a = *(const v2f*)(img1 + off);
      const v2f b = *(const v2f*)(img2 + off);
      val = (v4f){a.x, b.x, a.y, b.y};
    }
    *(v4f*)&s12[r][2 * p] = val;          // 16B aligned
  }
  __syncthreads();

  // ---- phase 2: horizontal blur of 5 quantities ----
  // elements: 42 rows x 32 cols = 1344
  for (int idx = tid; idx < IN_ROWS * TILE; idx += 256) {
    int r = idx >> 5;
    int c = idx & 31;
    v2f a01 = {0.f, 0.f};
    v2f a23 = {0.f, 0.f};
    float a4 = 0.f;
#pragma unroll
    for (int dx = 0; dx < 11; ++dx) {
      float w = c_g[dx];
      v2f v = s12[r][c + dx + 1];         // input col offset (RADX-RADY)=1
      a01 += w * v;
      v2f sq = v * v;
      a23 += w * sq;
      a4 += w * (v.x * v.y);
    }
    h01[r][c] = a01;
    h23[r][c] = a23;
    h4[r][c] = a4;
  }
  __syncthreads();

  // ---- phase 3: vertical blur, 4 consecutive rows per thread (sliding) ----
  const float C1 = 1e-4f;
  const float C2 = 9e-4f;
  const int c = tid & 31;
  const int r0 = (tid >> 5) * 4;          // 8 groups x 4 rows = 32 rows

  v2f m[4];   // (mu1, mu2)
  v2f vv[4];  // (b11, b22)
  float b12[4];
#pragma unroll
  for (int o = 0; o < 4; ++o) {
    m[o] = (v2f){0.f, 0.f};
    vv[o] = (v2f){0.f, 0.f};
    b12[o] = 0.f;
  }

#pragma unroll
  for (int dy = 0; dy < 14; ++dy) {
    v2f a = h01[r0 + dy][c];
    v2f b = h23[r0 + dy][c];
    float d = h4[r0 + dy][c];
#pragma unroll
    for (int o = 0; o < 4; ++o) {
      const int k = dy - o;
      if (k >= 0 && k < 11) {
        float w = c_g[k];
        m[o] += w * a;
        vv[o] += w * b;
        b12[o] += w * d;
      }
    }
  }

  float lsum = 0.f;
#pragma unroll
  for (int o = 0; o < 4; ++o) {
    float mu1 = m[o].x, mu2 = m[o].y;
    float mu1sq = mu1 * mu1;
    float mu2sq = mu2 * mu2;
    float mu12 = mu1 * mu2;
    float sig11 = vv[o].x - mu1sq;
    float sig22 = vv[o].y - mu2sq;
    float sig12 = b12[o] - mu12;
    float num = (2.f * mu12 + C1) * (2.f * sig12 + C2);
    float den = (mu1sq + mu2sq + C1) * (sig11 + sig22 + C2);
    lsum += num * __builtin_amdgcn_rcpf(den);
  }

  // wave (64-lane) reduction
#pragma unroll
  for (int off = 32; off > 0; off >>= 1)
    lsum += __shfl_down(lsum, off, 64);
  const int lane = tid & 63;
  const int wid = tid >> 6;
  if (lane == 0) wsum[wid] = lsum;
  __syncthreads();
  if (tid == 0) {
    float b = wsum[0] + wsum[1] + wsum[2] + wsum[3];
    int slot = (blockIdx.x + blockIdx.y * 16) & (NACC - 1);
    atomicAdd(acc + slot, b);
  }
}

__global__ void ssim_finalize_kernel(const float* __restrict__ acc,
                                     float* __restrict__ out) {
  __shared__ float wsum[4];
  const int tid = threadIdx.x;
  float s = acc[tid];
#pragma unroll
  for (int off = 32; off > 0; off >>= 1)
    s += __shfl_down(s, off, 64);
  if ((tid & 63) == 0) wsum[tid >> 6] = s;
  __syncthreads();
  if (tid == 0)
    out[0] = 1.0f - (wsum[0] + wsum[1] + wsum[2] + wsum[3]) * (1.0f / NPIX);
}

extern "C" void kernel_launch(void* const* d_in, const int* in_sizes, int n_in,
                              void* d_out, int out_size, void* d_ws, size_t ws_size,
                              hipStream_t stream) {
  const float* img1 = (const float*)d_in[0];
  const float* img2 = (const float*)d_in[1];
  float* out = (float*)d_out;
  float* acc = (float*)d_ws;

  hipMemsetAsync(acc, 0, NACC * sizeof(float), stream);

  dim3 grid(WW / TILE, HH / TILE, NPLANES);
  ssim_fused_kernel<<<grid, 256, 0, stream>>>(img1, img2, acc);
  ssim_finalize_kernel<<<1, NACC, 0, stream>>>(acc, out);
}